// Round 2
// baseline (1355.119 us; speedup 1.0000x reference)
//
#include <hip/hip_runtime.h>

typedef unsigned short u16;
typedef __attribute__((ext_vector_type(8))) __bf16 bf16x8;
typedef __attribute__((ext_vector_type(4))) float f32x4;

constexpr int C = 256;
constexpr int T = 4096;
constexpr int B = 4;
constexpr int NENC = 40;
constexpr int NDEC = 10;
constexpr int TILE = 64;

__device__ __forceinline__ float bf2f(u16 v) {
  union { unsigned u; float f; } x;
  x.u = ((unsigned)v) << 16;
  return x.f;
}
__device__ __forceinline__ u16 f2bf(float f) {
  union { float ff; unsigned u; } x;
  x.ff = f;
  unsigned r = x.u + 0x7fffu + ((x.u >> 16) & 1u);
  return (u16)(r >> 16);
}
// B1 LDS elem index; row stride 512 elems (1KB), 16B-granule XOR swizzle.
__device__ __forceinline__ int swz(int row, int col) {
  int g = ((row & 7) ^ (row >> 3)) & 7;
  return row * 512 + (col ^ (g << 3));
}

typedef __attribute__((address_space(1))) const unsigned int* gp1_t;
typedef __attribute__((address_space(3))) unsigned int* lp3_t;
__device__ __forceinline__ void gl_lds16(const u16* g, u16* l) {
  __builtin_amdgcn_global_load_lds((gp1_t)(const void*)g, (lp3_t)(void*)l, 16, 0, 0);
}

// Pack encoder phase-1 weights (Wf,Wg) into DMA-contiguous chunks:
// penc1[((layer*8+wave)*16+c)*2048 + s*512 + lane*8]; lane=(kgran<<4)|row.
__global__ void k_pack1(const float* __restrict__ Wf, const float* __restrict__ Wg,
                        u16* __restrict__ penc1, int total) {
  int p = blockIdx.x * 256 + threadIdx.x;
  if (p >= total) return;
  int lane = p & 63;
  int s = (p >> 6) & 3;
  int c = (p >> 8) & 15;
  int wv = (p >> 12) & 7;
  int layer = p >> 15;
  int co = wv * 32 + (s & 1) * 16 + (lane & 15);
  int k = c * 32 + (lane >> 4) * 8;
  const float* src = (s >= 2 ? Wg : Wf) + ((size_t)layer * C + co) * 512 + k;
  u16* dst = penc1 + (size_t)p * 8;
#pragma unroll
  for (int r = 0; r < 8; ++r) dst[r] = f2bf(src[r]);
}

// Pack encoder phase-2 (Wr): penc2[((layer*8+wave)*8+c)*1024 + s*512 + lane*8]
__global__ void k_pack2(const float* __restrict__ Wr, u16* __restrict__ penc2, int total) {
  int p = blockIdx.x * 256 + threadIdx.x;
  if (p >= total) return;
  int lane = p & 63;
  int s = (p >> 6) & 1;
  int c = (p >> 7) & 7;
  int wv = (p >> 10) & 7;
  int layer = p >> 13;
  int co = wv * 32 + s * 16 + (lane & 15);
  int k = c * 32 + (lane >> 4) * 8;
  const float* src = Wr + ((size_t)layer * C + co) * 256 + k;
  u16* dst = penc2 + (size_t)p * 8;
#pragma unroll
  for (int r = 0; r < 8; ++r) dst[r] = f2bf(src[r]);
}

// Pack decoder weights (tap-1 of f/g convs, r 1x1) + tdin.
// New layout for multi-block GEMV decoder:
//  pdfg[(layer*256+co)*512 + which*256 + pos], pos=(k&15)*16+(k>>4)  (k-interleave
//  so a thread's 16 weights for k=kofs+16j are 32B contiguous)
//  pdr [(layer*256+co)*256 + pos], same interleave.
__global__ void k_packd(const float* __restrict__ dWf, const float* __restrict__ dWg,
                        const float* __restrict__ dWr, const float* __restrict__ dinW,
                        u16* __restrict__ pdfg, u16* __restrict__ pdr,
                        u16* __restrict__ tdin) {
  int p = blockIdx.x * 256 + threadIdx.x;
  if (p < 163840) {
    int e0 = p * 8;
    int layer = e0 >> 17;
    int rem = e0 & 131071;
    int co = rem >> 9;
    int q = rem & 511;
    int which = q >> 8;
    int pos0 = q & 255;
    const float* src = (which ? dWg : dWf) + ((size_t)(layer * 256 + co)) * 512 + 1;
    u16* dst = pdfg + e0;
#pragma unroll
    for (int r = 0; r < 8; ++r) {
      int pos = pos0 + r;
      int k = ((pos & 15) << 4) | (pos >> 4);
      dst[r] = f2bf(src[2 * k]);
    }
  } else if (p < 245760) {
    int q = p - 163840;
    int e0 = q * 8;
    int layer = e0 >> 16;
    int rem = e0 & 65535;
    int co = rem >> 8;
    int pos0 = rem & 255;
    const float* src = dWr + ((size_t)(layer * 256 + co)) * 256;
    u16* dst = pdr + e0;
#pragma unroll
    for (int r = 0; r < 8; ++r) {
      int pos = pos0 + r;
      int k = ((pos & 15) << 4) | (pos >> 4);
      dst[r] = f2bf(src[k]);
    }
  } else if (p < 249856) {
    int u = p - 245760;
#pragma unroll
    for (int r = 0; r < 8; ++r) tdin[u * 8 + r] = f2bf(dinW[u * 8 + r]);
  }
}

__global__ void k_zero(float* __restrict__ p, int n) {
  int i = blockIdx.x * 256 + threadIdx.x;
  if (i < n) p[i] = 0.f;
}

__global__ void k_input(const float* __restrict__ x, const float* __restrict__ W,
                        const float* __restrict__ bin, float* __restrict__ h) {
  int idx = blockIdx.x * 256 + threadIdx.x;
  int t = idx & (T - 1);
  int c = (idx >> 12) & (C - 1);
  int b = idx >> 20;
  float xv = x[b * T + t];
  float xp = (t > 0) ? x[b * T + t - 1] : 0.f;
  h[idx] = W[2 * c] * xp + W[2 * c + 1] * xv + bin[c];
}

// Fused gated residual block. grid=256, block=512 (8 waves).
// Weight K-chunk order is staggered per XCD-local block index so the 32 CUs
// of an XCD hit different L2 banks instead of serializing on one address.
__global__ __launch_bounds__(512, 2) void k_enc(
    const float* __restrict__ hin, float* __restrict__ hout, float* __restrict__ rowsum_l,
    const u16* __restrict__ pw1, const float* __restrict__ bfb,
    const float* __restrict__ bgb,
    const u16* __restrict__ pw2, const float* __restrict__ brb,
    int dil) {
  extern __shared__ __align__(16) u16 smem[];
  u16* wb = smem + 64 * 512;
  const int tid = threadIdx.x;
  const int wave = tid >> 6;
  const int lane = tid & 63;
  const int ncol = lane & 15;
  const int quad = lane >> 4;
  const int wg = blockIdx.x;
  const int b = wg >> 6;
  const int t0 = (wg & 63) * TILE;
  const float* hb = hin + b * C * T;

  const int co0 = wave * 32;
  const int kq = quad * 8;
  const int off1 = (wg >> 3) & 15;   // stagger start chunk (XCD-local index)
  const int off2 = (wg >> 3) & 7;
  const u16* b1 = pw1 + wave * 32768 + lane * 8;   // contiguous DMA source, phase 1
  const u16* b2 = pw2 + wave * 8192 + lane * 8;    // phase 2
  u16* wreg0 = wb + wave * 2048;
  u16* wreg1 = wb + 16384 + wave * 2048;
  const int aoff = lane * 8;

  // ---- issue phase-1 chunks off1, off1+1 ----
#pragma unroll
  for (int cc = 0; cc < 2; ++cc) {
    u16* ld = cc ? wreg1 : wreg0;
    const u16* gs = b1 + ((off1 + cc) & 15) * 2048;
    gl_lds16(gs, ld);
    gl_lds16(gs + 512, ld + 512);
    gl_lds16(gs + 1024, ld + 1024);
    gl_lds16(gs + 1536, ld + 1536);
  }

  // ---- stage B1: smem[n][2ci+tap] ----
  const int n4 = tid & 15;
  const int cib = tid >> 4;
  float4 v[16];
  const bool al4 = ((dil & 3) == 0);
  if (t0 >= dil) {
#pragma unroll
    for (int it2 = 0; it2 < 16; ++it2) {
      int ci = (cib + it2 * 32) & 255;
      int tap = it2 >> 3;
      int tb = t0 + n4 * 4 - (tap ? 0 : dil);
      const float* p = hb + ci * T + tb;
      if (tap || al4) {
        v[it2] = *(const float4*)p;
      } else {
        v[it2].x = p[0]; v[it2].y = p[1]; v[it2].z = p[2]; v[it2].w = p[3];
      }
    }
  } else {
#pragma unroll
    for (int it2 = 0; it2 < 16; ++it2) {
      int ci = (cib + it2 * 32) & 255;
      int tap = it2 >> 3;
      int tb = t0 + n4 * 4 - (tap ? 0 : dil);
      const float* p = hb + ci * T + tb;
      if (tap) {
        v[it2] = *(const float4*)p;
      } else {
        v[it2].x = (tb + 0 >= 0) ? p[0] : 0.f;
        v[it2].y = (tb + 1 >= 0) ? p[1] : 0.f;
        v[it2].z = (tb + 2 >= 0) ? p[2] : 0.f;
        v[it2].w = (tb + 3 >= 0) ? p[3] : 0.f;
      }
    }
  }
#pragma unroll
  for (int it2 = 0; it2 < 8; ++it2) {
    int ci = (cib + it2 * 32) & 255;
    const float* p0 = (const float*)&v[it2];
    const float* p1 = (const float*)&v[it2 + 8];
#pragma unroll
    for (int r = 0; r < 4; ++r) {
      unsigned w32;
      asm("v_cvt_pk_bf16_f32 %0, %1, %2" : "=v"(w32) : "v"(p0[r]), "v"(p1[r]));
      *(unsigned*)(&smem[swz(n4 * 4 + r, 2 * ci)]) = w32;
    }
  }
  __syncthreads();   // drains vmcnt(0): first two chunks landed

  // ---- phase 1: [f;g] = W_fg @ B1, M=512 K=512 N=64 (staggered chunk order) ----
  f32x4 acc[4][4];
#pragma unroll
  for (int m = 0; m < 4; ++m)
#pragma unroll
    for (int nt = 0; nt < 4; ++nt)
      acc[m][nt] = (f32x4){0.f, 0.f, 0.f, 0.f};

#pragma unroll
  for (int c = 0; c < 16; ++c) {
    if (c < 15) asm volatile("s_waitcnt vmcnt(4)" ::: "memory");
    else        asm volatile("s_waitcnt vmcnt(0)" ::: "memory");
    const u16* wr_ = (c & 1) ? wreg1 : wreg0;
    bf16x8 af0 = *(const bf16x8*)(wr_ + aoff);
    bf16x8 af1 = *(const bf16x8*)(wr_ + 512 + aoff);
    bf16x8 af2 = *(const bf16x8*)(wr_ + 1024 + aoff);
    bf16x8 af3 = *(const bf16x8*)(wr_ + 1536 + aoff);
    const int kk = ((c + off1) & 15) * 32 + kq;
    bf16x8 bfr[4];
#pragma unroll
    for (int nt = 0; nt < 4; ++nt)
      bfr[nt] = *(const bf16x8*)(&smem[swz(nt * 16 + ncol, kk)]);
#pragma unroll
    for (int nt = 0; nt < 4; ++nt) {
      acc[0][nt] = __builtin_amdgcn_mfma_f32_16x16x32_bf16(af0, bfr[nt], acc[0][nt], 0, 0, 0);
      acc[1][nt] = __builtin_amdgcn_mfma_f32_16x16x32_bf16(af1, bfr[nt], acc[1][nt], 0, 0, 0);
      acc[2][nt] = __builtin_amdgcn_mfma_f32_16x16x32_bf16(af2, bfr[nt], acc[2][nt], 0, 0, 0);
      acc[3][nt] = __builtin_amdgcn_mfma_f32_16x16x32_bf16(af3, bfr[nt], acc[3][nt], 0, 0, 0);
    }
    if (c + 2 < 16) {
      asm volatile("s_waitcnt lgkmcnt(0)" ::: "memory");
      u16* ld = (c & 1) ? wreg1 : wreg0;
      const u16* gs = b1 + ((c + 2 + off1) & 15) * 2048;
      gl_lds16(gs, ld);
      gl_lds16(gs + 512, ld + 512);
      gl_lds16(gs + 1024, ld + 1024);
      gl_lds16(gs + 1536, ld + 1536);
    }
  }

  // ---- issue phase-2 (res-only) chunks off2, off2+1 ----
#pragma unroll
  for (int cc = 0; cc < 2; ++cc) {
    u16* ld = cc ? wreg1 : wreg0;
    const u16* gs = b2 + ((off2 + cc) & 7) * 1024;
    gl_lds16(gs, ld);
    gl_lds16(gs + 512, ld + 512);
  }
  __syncthreads();   // B1 reads done + p2 first chunks landed

  // ---- gating -> B2[k=co][n] in LDS, plus row-sum accumulation for skip ----
  float* rsb = rowsum_l + b * C;
#pragma unroll
  for (int j = 0; j < 2; ++j) {
    const int cob = co0 + j * 16 + quad * 4;
    float bfv[4], bgv[4], rs[4], ov[4];
#pragma unroll
    for (int r = 0; r < 4; ++r) {
      bfv[r] = bfb[cob + r];
      bgv[r] = bgb[cob + r];
      rs[r] = 0.f;
    }
#pragma unroll
    for (int nt = 0; nt < 4; ++nt) {
      const int n = nt * 16 + ncol;
#pragma unroll
      for (int r = 0; r < 4; ++r) {
        float fv = acc[j][nt][r] + bfv[r];
        float gv = acc[2 + j][nt][r] + bgv[r];
        float th = 1.f - 2.f / (__expf(2.f * fv) + 1.f);
        float sg = 1.f / (1.f + __expf(-gv));
        float o = th * sg;
        rs[r] += o;
        ov[r] = o;
      }
      uint2 w;
      asm("v_cvt_pk_bf16_f32 %0, %1, %2" : "=v"(w.x) : "v"(ov[0]), "v"(ov[1]));
      asm("v_cvt_pk_bf16_f32 %0, %1, %2" : "=v"(w.y) : "v"(ov[2]), "v"(ov[3]));
      *(uint2*)(&smem[swz(n, cob)]) = w;
    }
#pragma unroll
    for (int r = 0; r < 4; ++r) {
      float s = rs[r];
      s += __shfl_xor(s, 1);
      s += __shfl_xor(s, 2);
      s += __shfl_xor(s, 4);
      s += __shfl_xor(s, 8);
      if (ncol == 0) atomicAdd(&rsb[cob + r], s);
    }
  }
  __syncthreads();

  // ---- phase 2: res = Wr @ out, M=256 K=256 N=64 (staggered) ----
  f32x4 acc2[2][4];
#pragma unroll
  for (int m = 0; m < 2; ++m)
#pragma unroll
    for (int nt = 0; nt < 4; ++nt)
      acc2[m][nt] = (f32x4){0.f, 0.f, 0.f, 0.f};

#pragma unroll
  for (int c = 0; c < 8; ++c) {
    if (c < 7) asm volatile("s_waitcnt vmcnt(2)" ::: "memory");
    else       asm volatile("s_waitcnt vmcnt(0)" ::: "memory");
    const u16* wr_ = (c & 1) ? wreg1 : wreg0;
    bf16x8 af0 = *(const bf16x8*)(wr_ + aoff);
    bf16x8 af1 = *(const bf16x8*)(wr_ + 512 + aoff);
    const int kk = ((c + off2) & 7) * 32 + kq;
    bf16x8 bfr[4];
#pragma unroll
    for (int nt = 0; nt < 4; ++nt)
      bfr[nt] = *(const bf16x8*)(&smem[swz(nt * 16 + ncol, kk)]);
#pragma unroll
    for (int nt = 0; nt < 4; ++nt) {
      acc2[0][nt] = __builtin_amdgcn_mfma_f32_16x16x32_bf16(af0, bfr[nt], acc2[0][nt], 0, 0, 0);
      acc2[1][nt] = __builtin_amdgcn_mfma_f32_16x16x32_bf16(af1, bfr[nt], acc2[1][nt], 0, 0, 0);
    }
    if (c + 2 < 8) {
      asm volatile("s_waitcnt lgkmcnt(0)" ::: "memory");
      u16* ld = (c & 1) ? wreg1 : wreg0;
      const u16* gs = b2 + ((c + 2 + off2) & 7) * 1024;
      gl_lds16(gs, ld);
      gl_lds16(gs + 512, ld + 512);
    }
  }
  __syncthreads();   // all waves done reading B2; LDS free for transpose

  // ---- epilogue: transpose res through LDS (f32, stride 66), float4 stores ----
  float* fb = (float*)smem;   // [256][66] f32
#pragma unroll
  for (int m = 0; m < 2; ++m) {
    const int cob = co0 + m * 16 + quad * 4;
#pragma unroll
    for (int nt = 0; nt < 4; ++nt) {
      const int t = nt * 16 + ncol;
#pragma unroll
      for (int r = 0; r < 4; ++r)
        fb[(cob + r) * 66 + t] = acc2[m][nt][r] + brb[cob + r];
    }
  }
  __syncthreads();
  float* ho = hout + b * C * T;
#pragma unroll
  for (int it2 = 0; it2 < 8; ++it2) {
    const int ci = cib + it2 * 32;
    const float* fr = fb + ci * 66 + n4 * 4;
    float4 o;
    o.x = fr[0] + v[it2 + 8].x;
    o.y = fr[1] + v[it2 + 8].y;
    o.z = fr[2] + v[it2 + 8].z;
    o.w = fr[3] + v[it2 + 8].w;
    *(float4*)(ho + ci * T + t0 + n4 * 4) = o;
  }
}

// per-layer skip matvec: pooled[b][co] += Ws_l[co,:] . rowsum[l][b,:] + T*bs_l[co]
__global__ __launch_bounds__(256) void k_skip(
    const float* __restrict__ encWs, const float* __restrict__ encbs,
    const float* __restrict__ rowsum, float* __restrict__ pooled) {
  __shared__ float rs[B][C];
  const int l = blockIdx.x;
  const int co = threadIdx.x;
  for (int i = co; i < B * C; i += 256) rs[i >> 8][i & 255] = rowsum[l * B * C + i];
  __syncthreads();
  const float* Wrow = encWs + (size_t)l * C * C + co * C;
  float bs = encbs[l * C + co] * (float)T;
  float d[B] = {0.f, 0.f, 0.f, 0.f};
  for (int ci = 0; ci < C; ci += 4) {
    float4 w = *(const float4*)(Wrow + ci);
#pragma unroll
    for (int b = 0; b < B; ++b)
      d[b] += w.x * rs[b][ci] + w.y * rs[b][ci + 1] + w.z * rs[b][ci + 2] + w.w * rs[b][ci + 3];
  }
#pragma unroll
  for (int b = 0; b < B; ++b) atomicAdd(&pooled[b * C + co], d[b] + bs);
}

// wave-per-dot FC
__global__ __launch_bounds__(256) void k_fc(
    const float* __restrict__ pooled,
    const float* __restrict__ muW, const float* __restrict__ mub,
    const float* __restrict__ lvW, const float* __restrict__ lvb,
    float* __restrict__ mlbuf, float* __restrict__ dout) {
  __shared__ float pm[B * C];
  const int tid = threadIdx.x;
  for (int i = tid; i < B * C; i += 256) pm[i] = pooled[i] * (1.f / (float)T);
  __syncthreads();
  const int waveG = blockIdx.x * 4 + (tid >> 6);
  const int lane = tid & 63;
  for (int j = 0; j < 16; ++j) {
    int d = waveG * 16 + j;
    int b = d >> 8, r = d & 255, which = r >> 7, l = r & 127;
    const float* Wrow = (which ? lvW : muW) + l * C;
    const float* p = pm + b * C;
    float s = Wrow[lane] * p[lane] + Wrow[lane + 64] * p[lane + 64] +
              Wrow[lane + 128] * p[lane + 128] + Wrow[lane + 192] * p[lane + 192];
#pragma unroll
    for (int off = 32; off; off >>= 1) s += __shfl_xor(s, off);
    if (lane == 0) {
      float val = s + (which ? lvb[l] : mub[l]);
      mlbuf[which * 512 + b * 128 + l] = val;
      dout[4 + which * 512 + b * 128 + l] = val;
    }
  }
}

// ---------------- multi-block decoder ----------------
// 16 blocks x 256 threads; block owns 16 output channels per GEMV stage.
// Cross-block sync: monotonic per-stage arrival counters (agent scope), so
// rocprof kernel replay (counters already >= 16) sails through, no deadlock.
struct WSet { uint4 f0, f1, g0, g1; };
__device__ __forceinline__ WSet load_fg(const u16* __restrict__ pdfg, int L, int co, int kofs) {
  const u16* pf = pdfg + ((size_t)(L * 256 + co)) * 512 + kofs * 16;
  WSet s;
  s.f0 = *(const uint4*)pf;
  s.f1 = *(const uint4*)(pf + 8);
  s.g0 = *(const uint4*)(pf + 256);
  s.g1 = *(const uint4*)(pf + 264);
  return s;
}
__device__ __forceinline__ float gate_fn(float fv, float gv) {
  float th = 1.f - 2.f / (__expf(2.f * fv) + 1.f);
  float sg = 1.f / (1.f + __expf(-gv));
  return th * sg;
}
__device__ __forceinline__ void gbar_sync(int* __restrict__ bar, int idx, int nblk) {
  __threadfence();
  __syncthreads();
  if (threadIdx.x == 0) {
    __hip_atomic_fetch_add(&bar[idx], 1, __ATOMIC_ACQ_REL, __HIP_MEMORY_SCOPE_AGENT);
    while (__hip_atomic_load(&bar[idx], __ATOMIC_ACQUIRE, __HIP_MEMORY_SCOPE_AGENT) < nblk)
      __builtin_amdgcn_s_sleep(1);
  }
  __syncthreads();
}

// dot over thread's 16 k-slots (k = kofs + 16j) against LDS rows S[b][*]
#define DOT16(a0, a1, a2, a3, W0, W1, S)                                   \
  do {                                                                     \
    const unsigned uu[8] = {W0.x, W0.y, W0.z, W0.w, W1.x, W1.y, W1.z, W1.w}; \
    _Pragma("unroll") for (int m = 0; m < 8; ++m) {                        \
      float wl = bf2f((u16)(uu[m] & 0xffffu));                             \
      float wh = bf2f((u16)(uu[m] >> 16));                                 \
      int k0 = kofs + 32 * m, k1 = k0 + 16;                                \
      a0 += wl * S[0][k0] + wh * S[0][k1];                                 \
      a1 += wl * S[1][k0] + wh * S[1][k1];                                 \
      a2 += wl * S[2][k0] + wh * S[2][k1];                                 \
      a3 += wl * S[3][k0] + wh * S[3][k1];                                 \
    }                                                                      \
  } while (0)

#define RED16(x)            \
  do {                      \
    x += __shfl_xor(x, 1);  \
    x += __shfl_xor(x, 2);  \
    x += __shfl_xor(x, 4);  \
    x += __shfl_xor(x, 8);  \
  } while (0)

__global__ __launch_bounds__(256, 1) void k_dec2(
    const float* __restrict__ mlbuf, const float* __restrict__ eps,
    const u16* __restrict__ tdin, const float* __restrict__ dinb,
    const u16* __restrict__ pdfg, const float* __restrict__ dbf,
    const float* __restrict__ dbg,
    const u16* __restrict__ pdr, const float* __restrict__ dbr,
    const float* __restrict__ outW, const float* __restrict__ outb,
    float* __restrict__ dout, int* __restrict__ gbar,
    float* __restrict__ gout, float* __restrict__ gh) {
  __shared__ float zs[4][128];
  __shared__ float hs[4][256];
  __shared__ float os[4][256];
  __shared__ float red[4][4];
  const int tid = threadIdx.x;
  const int blk = blockIdx.x;
  const int kofs = tid & 15;
  const int co = blk * 16 + (tid >> 4);

  // z = mu + eps*exp(0.5*logvar)  (redundant per block)
  for (int u = tid; u < 512; u += 256) {
    int b = u >> 7, l = u & 127;
    zs[b][l] = mlbuf[b * 128 + l] + eps[b * 128 + l] * expf(0.5f * mlbuf[512 + b * 128 + l]);
  }
  __syncthreads();

  // dec_in: h0[tid] for all 4 batches (redundant per block -> no barrier)
  {
    float a0 = 0.f, a1 = 0.f, a2 = 0.f, a3 = 0.f;
    const u16* wp = tdin + tid * 128;
#pragma unroll 4
    for (int k = 0; k < 128; k += 2) {
      unsigned ww = *(const unsigned*)(wp + k);
      float w0 = bf2f((u16)(ww & 0xffffu)), w1 = bf2f((u16)(ww >> 16));
      a0 += w0 * zs[0][k] + w1 * zs[0][k + 1];
      a1 += w0 * zs[1][k] + w1 * zs[1][k + 1];
      a2 += w0 * zs[2][k] + w1 * zs[2][k + 1];
      a3 += w0 * zs[3][k] + w1 * zs[3][k + 1];
    }
    float bi = dinb[tid];
    hs[0][tid] = a0 + bi;
    hs[1][tid] = a1 + bi;
    hs[2][tid] = a2 + bi;
    hs[3][tid] = a3 + bi;
  }
  __syncthreads();

  WSet cur = load_fg(pdfg, 0, co, kofs);
  for (int i = 0; i < NDEC; ++i) {
    // R weights for this layer: consumed after the FG barrier (latency hidden)
    const u16* pr = pdr + ((size_t)(i * 256 + co)) * 256 + kofs * 16;
    uint4 rw0 = *(const uint4*)pr;
    uint4 rw1 = *(const uint4*)(pr + 8);

    float f0 = 0.f, f1 = 0.f, f2 = 0.f, f3 = 0.f;
    float g0 = 0.f, g1 = 0.f, g2 = 0.f, g3 = 0.f;
    DOT16(f0, f1, f2, f3, cur.f0, cur.f1, hs);
    DOT16(g0, g1, g2, g3, cur.g0, cur.g1, hs);
    // prefetch next layer's FG weights; lands during barrier + R phase
    WSet nxt = load_fg(pdfg, (i + 1 < NDEC) ? i + 1 : NDEC - 1, co, kofs);
    RED16(f0); RED16(f1); RED16(f2); RED16(f3);
    RED16(g0); RED16(g1); RED16(g2); RED16(g3);
    float bfv = dbf[i * 256 + co], bgv = dbg[i * 256 + co];
    float o0 = gate_fn(f0 + bfv, g0 + bgv);
    float o1 = gate_fn(f1 + bfv, g1 + bgv);
    float o2 = gate_fn(f2 + bfv, g2 + bgv);
    float o3 = gate_fn(f3 + bfv, g3 + bgv);
    {
      int r = tid & 15;
      float ov = r == 0 ? o0 : r == 1 ? o1 : r == 2 ? o2 : o3;
      if (r < 4) gout[r * 256 + co] = ov;
    }
    gbar_sync(gbar, 2 * i, 16);
#pragma unroll
    for (int u = 0; u < 4; ++u)
      os[u][tid] = __hip_atomic_load(&gout[tid + u * 256], __ATOMIC_RELAXED,
                                     __HIP_MEMORY_SCOPE_AGENT);
    __syncthreads();

    float r0 = 0.f, r1 = 0.f, r2 = 0.f, r3 = 0.f;
    DOT16(r0, r1, r2, r3, rw0, rw1, os);
    RED16(r0); RED16(r1); RED16(r2); RED16(r3);
    float brv = dbr[i * 256 + co];
    float h0 = hs[0][co] + r0 + brv;
    float h1 = hs[1][co] + r1 + brv;
    float h2 = hs[2][co] + r2 + brv;
    float h3 = hs[3][co] + r3 + brv;
    {
      int r = tid & 15;
      float hv = r == 0 ? h0 : r == 1 ? h1 : r == 2 ? h2 : h3;
      if (r < 4) gh[r * 256 + co] = hv;
    }
    gbar_sync(gbar, 2 * i + 1, 16);
#pragma unroll
    for (int u = 0; u < 4; ++u)
      hs[u][tid] = __hip_atomic_load(&gh[tid + u * 256], __ATOMIC_RELAXED,
                                     __HIP_MEMORY_SCOPE_AGENT);
    __syncthreads();
    cur = nxt;
  }

  if (blk == 0) {
    float w = outW[tid];
    float v0 = w * hs[0][tid], v1 = w * hs[1][tid];
    float v2 = w * hs[2][tid], v3 = w * hs[3][tid];
#pragma unroll
    for (int off = 32; off; off >>= 1) {
      v0 += __shfl_xor(v0, off);
      v1 += __shfl_xor(v1, off);
      v2 += __shfl_xor(v2, off);
      v3 += __shfl_xor(v3, off);
    }
    if ((tid & 63) == 0) {
      int wv = tid >> 6;
      red[wv][0] = v0; red[wv][1] = v1; red[wv][2] = v2; red[wv][3] = v3;
    }
    __syncthreads();
    if (tid < 4)
      dout[tid] = red[0][tid] + red[1][tid] + red[2][tid] + red[3][tid] + outb[0];
  }
}

extern "C" void kernel_launch(void* const* d_in, const int* in_sizes, int n_in,
                              void* d_out, int out_size, void* d_ws, size_t ws_size,
                              hipStream_t stream) {
  const float* x      = (const float*)d_in[0];
  const float* eps    = (const float*)d_in[1];
  const float* encinW = (const float*)d_in[2];
  const float* encinb = (const float*)d_in[3];
  const float* encWf  = (const float*)d_in[4];
  const float* encbf  = (const float*)d_in[5];
  const float* encWg  = (const float*)d_in[6];
  const float* encbg  = (const float*)d_in[7];
  const float* encWr  = (const float*)d_in[8];
  const float* encbr  = (const float*)d_in[9];
  const float* encWs  = (const float*)d_in[10];
  const float* encbs  = (const float*)d_in[11];
  const float* muW    = (const float*)d_in[12];
  const float* mub    = (const float*)d_in[13];
  const float* lvW    = (const float*)d_in[14];
  const float* lvb    = (const float*)d_in[15];
  const float* dinW   = (const float*)d_in[16];
  const float* dinb   = (const float*)d_in[17];
  const float* dWf    = (const float*)d_in[18];
  const float* dbf    = (const float*)d_in[19];
  const float* dWg    = (const float*)d_in[20];
  const float* dbg    = (const float*)d_in[21];
  const float* dWr    = (const float*)d_in[22];
  const float* dbr    = (const float*)d_in[23];
  const float* outW   = (const float*)d_in[24];
  const float* outb   = (const float*)d_in[25];
  float* dout = (float*)d_out;

  char* ws = (char*)d_ws;
  float* hA = (float*)ws;
  float* hB = hA + (size_t)B * C * T;
  float* pooled = hB + (size_t)B * C * T;
  float* mlbuf = pooled + B * C;
  int* gbar = (int*)(mlbuf + 1024);                 // 32 ints (20 used)
  float* goutb = (float*)(gbar + 32);               // [4][256]
  float* ghb = goutb + 1024;                        // [4][256]
  float* rowsum = ghb + 1024;                       // [40][4][256] f32
  u16* penc1 = (u16*)(rowsum + NENC * B * C);       // 10,485,760
  u16* penc2 = penc1 + (size_t)10485760;            // 2,621,440
  u16* pdfg = penc2 + (size_t)2621440;              // 1,310,720
  u16* pdr = pdfg + (size_t)1310720;                // 655,360
  u16* tdin = pdr + (size_t)655360;                 // 32,768

  (void)hipFuncSetAttribute(reinterpret_cast<const void*>(k_enc),
                            hipFuncAttributeMaxDynamicSharedMemorySize, 131072);

  k_pack1<<<(1310720 + 255) / 256, 256, 0, stream>>>(encWf, encWg, penc1, 1310720);
  k_pack2<<<(327680 + 255) / 256, 256, 0, stream>>>(encWr, penc2, 327680);
  k_packd<<<(249856 + 255) / 256, 256, 0, stream>>>(dWf, dWg, dWr, dinW, pdfg, pdr, tdin);

  // zero: pooled(1024) + mlbuf(1024) + gbar/gout/gh(2080) + rowsum(40960)
  const int nZ = 1024 + 1024 + 2080 + NENC * B * C;
  k_zero<<<(nZ + 255) / 256, 256, 0, stream>>>(pooled, nZ);
  k_input<<<(B * C * T) / 256, 256, 0, stream>>>(x, encinW, encinb, hA);

  for (int i = 0; i < NENC; ++i) {
    const int dil = 1 << (i % 10);
    const float* hi = (i & 1) ? hB : hA;
    float* ho = (i & 1) ? hA : hB;
    k_enc<<<256, 512, 131072, stream>>>(
        hi, ho, rowsum + (size_t)i * B * C,
        penc1 + (size_t)i * 262144, encbf + (size_t)i * C,
        encbg + (size_t)i * C,
        penc2 + (size_t)i * 65536, encbr + (size_t)i * C,
        dil);
  }

  k_skip<<<NENC, 256, 0, stream>>>(encWs, encbs, rowsum, pooled);
  k_fc<<<16, 256, 0, stream>>>(pooled, muW, mub, lvW, lvb, mlbuf, dout);
  k_dec2<<<16, 256, 0, stream>>>(mlbuf, eps, tdin, dinb, pdfg, dbf, dbg,
                                 pdr, dbr, outW, outb, dout, gbar, goutb, ghb);
}